// Round 6
// baseline (774.674 us; speedup 1.0000x reference)
//
#include <hip/hip_runtime.h>
#include <hip/hip_bf16.h>
#include <stdint.h>

typedef __hip_bfloat16 bf16;
typedef __bf16 bf16x8 __attribute__((ext_vector_type(8)));
typedef float f32x4 __attribute__((ext_vector_type(4)));

#define NB 1024
#define NM 4096
#define NZ 64
#define NH 8192

__device__ __forceinline__ float bf2f(bf16 x) { return __bfloat162float(x); }
__device__ __forceinline__ bf16 f2bf(float x) { return __float2bfloat16(x); }
__device__ __forceinline__ float sigf(float x) { return 1.f / (1.f + __expf(-x)); }

// async global->LDS, 16B per lane; LDS base wave-uniform, HW scatters lane L to base+16L.
__device__ __forceinline__ void gload16(const void* g, void* l) {
  __builtin_amdgcn_global_load_lds((const __attribute__((address_space(1))) unsigned int*)g,
                                   (__attribute__((address_space(3))) unsigned int*)l,
                                   16, 0, 0);
}

// fp32 x -> bf16 (4 elements/thread)
__global__ __launch_bounds__(256) void cvt_f32_bf16(const float* __restrict__ src,
                                                    bf16* __restrict__ dst, int n4) {
  const int i = blockIdx.x * 256 + threadIdx.x;
  if (i >= n4) return;
  const float4 v = ((const float4*)src)[i];
  bf16 o[4] = {f2bf(v.x), f2bf(v.y), f2bf(v.z), f2bf(v.w)};
  *(short4*)&dst[i * 4] = *(short4*)o;
}

__global__ void zero_f32(float* p, int n) {
  int i = blockIdx.x * blockDim.x + threadIdx.x;
  if (i < n) p[i] = 0.f;
}

// ---------------------------------------------------------------------------
// MFMA NT GEMM, encoder layers: C[r,c] = relu( sum_k A[r,k]*W[c,k] + bias[c] )
// A bf16, W fp32 (cvt in fragment build), C bf16. Tile 128x128, BK=64,
// 512 thr = 8 waves (wave -> 32x64 C). global_load_lds width-16 staging.
// XCD swizzle: with round-robin block->XCD (id%8), give XCD k col-tiles
// {k, k+8, ...} so 8 in-flight blocks share each W tile via L2.
// ---------------------------------------------------------------------------
__global__ __launch_bounds__(512) void gemm_nt(const bf16* __restrict__ A,
                                               const float* __restrict__ W,
                                               const float* __restrict__ bias,
                                               bf16* __restrict__ C,
                                               int K, int N) {
  __shared__ __attribute__((aligned(16))) bf16  smA[128 * 64];   // 16 KB
  __shared__ __attribute__((aligned(16))) float smW[128 * 64];   // 32 KB fp32
  const int tid  = threadIdx.x;
  const int lane = tid & 63;
  const int w    = tid >> 6;   // 0..7
  const int wr   = w >> 1;     // 0..3 : 32-row group
  const int wc   = w & 1;      // 0..1 : 64-col group

  // tile swizzle (performance heuristic only; any mapping is correct)
  const int id = blockIdx.x + (int)gridDim.x * blockIdx.y;  // gridDim.x == 8
  const int xcd = id & 7;
  const int s   = id >> 3;
  const int ycl = (N >> 7) >> 3;            // col-tiles per XCD cluster
  const int row0 = (s / ycl) * 128;
  const int col0 = ((s % ycl) * 8 + xcd) * 128;

  f32x4 acc[2][4];
#pragma unroll
  for (int i = 0; i < 2; i++)
#pragma unroll
    for (int j = 0; j < 4; j++) acc[i][j] = (f32x4){0.f, 0.f, 0.f, 0.f};

  const int rA = lane >> 3;        // A: row within 8-row granule-chunk
  const int kA = (lane & 7) * 8;   // A: k elem offset (16B granules)
  const int rW = lane >> 4;        // W: row within 4-row granule-chunk
  const int kW = (lane & 15) * 4;  // W: k elem offset (16B fp32 granules)

  for (int k0 = 0; k0 < K; k0 += 64) {
    __syncthreads();   // previous tile's LDS reads done
    // A tile: 1024 granules, 2/thread; wave w covers granules [256w, 256w+128)
#pragma unroll
    for (int c = 0; c < 2; c++) {
      const int chunk = 2 * w + c;                 // 8-row chunk 0..15
      gload16(A + (size_t)(row0 + chunk * 8 + rA) * K + (k0 + kA),
              &smA[chunk * 512]);
    }
    // W tile fp32: 2048 granules, 4/thread; granule g: row=g>>4, k4=(g&15)*4
#pragma unroll
    for (int c = 0; c < 4; c++) {
      const int row = w * 16 + c * 4 + rW;
      gload16(W + (size_t)(col0 + row) * K + (k0 + kW),
              &smW[w * 1024 + c * 256]);
    }
    __syncthreads();   // tile visible (compiler drains vmcnt before barrier)

#pragma unroll
    for (int ks = 0; ks < 64; ks += 32) {
      const int koff = ks + (lane >> 4) * 8;   // frag: [m|n = lane&15][k = quad*8+j]
      bf16x8 af[2], bfr[4];
#pragma unroll
      for (int i = 0; i < 2; i++)
        af[i] = *(const bf16x8*)&smA[(wr * 32 + i * 16 + (lane & 15)) * 64 + koff];
#pragma unroll
      for (int j = 0; j < 4; j++) {
        const int row = wc * 64 + j * 16 + (lane & 15);
        const f32x4 w0 = *(const f32x4*)&smW[row * 64 + koff];
        const f32x4 w1 = *(const f32x4*)&smW[row * 64 + koff + 4];
        bf16 t[8] = {f2bf(w0[0]), f2bf(w0[1]), f2bf(w0[2]), f2bf(w0[3]),
                     f2bf(w1[0]), f2bf(w1[1]), f2bf(w1[2]), f2bf(w1[3])};
        bfr[j] = *(bf16x8*)t;
      }
#pragma unroll
      for (int i = 0; i < 2; i++)
#pragma unroll
        for (int j = 0; j < 4; j++)
          acc[i][j] = __builtin_amdgcn_mfma_f32_16x16x32_bf16(af[i], bfr[j], acc[i][j], 0, 0, 0);
    }
  }

  // C/D layout: col = lane&15, row = (lane>>4)*4 + t   [m89-verified]
#pragma unroll
  for (int i = 0; i < 2; i++) {
#pragma unroll
    for (int j = 0; j < 4; j++) {
      const int cc = col0 + wc * 64 + j * 16 + (lane & 15);
      const float bs = bias[cc];
#pragma unroll
      for (int t = 0; t < 4; t++) {
        const int rr = row0 + wr * 32 + i * 16 + (lane >> 4) * 4 + t;
        float v = acc[i][j][t] + bs;
        v = v > 0.f ? v : 0.f;   // relu
        C[(size_t)rr * N + cc] = f2bf(v);
      }
    }
  }
}

// ---------------------------------------------------------------------------
// mu/logvar split-K: zpre[b, 0..63]=mu-dot, [64..127]=lv-dot (fp32 atomics).
// A = h2 bf16, weights fp32. grid (16 b-tiles, 16 k-chunks of 256), block 256.
// ---------------------------------------------------------------------------
__global__ __launch_bounds__(256) void mulv_splitk(const bf16* __restrict__ h2,
                                                   const float* __restrict__ muw,
                                                   const float* __restrict__ lvw,
                                                   float* __restrict__ zpre) {
  __shared__ float sA[32][64];    // [k][b]
  __shared__ float sW[32][128];   // [k][j]
  const int tid = threadIdx.x;
  const int b0 = blockIdx.x * 64;
  const int k0 = blockIdx.y * 256;
  const int tj = tid & 15;        // 8 j's each
  const int tb = tid >> 4;        // 4 b's each
  float acc[4][8];
#pragma unroll
  for (int i = 0; i < 4; i++)
#pragma unroll
    for (int j = 0; j < 8; j++) acc[i][j] = 0.f;

  const int lb = tid >> 2, lk = (tid & 3) * 8;    // h2 loader
  const int wj = tid >> 1, wk = (tid & 1) * 16;   // weight loader
  const float* wrow = (wj < 64) ? (muw + (size_t)wj * NM) : (lvw + (size_t)(wj - 64) * NM);

  for (int kc = 0; kc < 256; kc += 32) {
    __syncthreads();
    {
      const bf16* p = h2 + (size_t)(b0 + lb) * NM + (k0 + kc + lk);
#pragma unroll
      for (int i = 0; i < 8; i++) sA[lk + i][lb] = bf2f(p[i]);
      const float* q = wrow + (k0 + kc + wk);
#pragma unroll
      for (int i = 0; i < 16; i++) sW[wk + i][wj] = q[i];
    }
    __syncthreads();
#pragma unroll
    for (int k = 0; k < 32; k++) {
      float av[4], wv[8];
#pragma unroll
      for (int i = 0; i < 4; i++) av[i] = sA[k][tb * 4 + i];
#pragma unroll
      for (int j = 0; j < 8; j++) wv[j] = sW[k][tj * 8 + j];
#pragma unroll
      for (int i = 0; i < 4; i++)
#pragma unroll
        for (int j = 0; j < 8; j++) acc[i][j] += av[i] * wv[j];
    }
  }
#pragma unroll
  for (int i = 0; i < 4; i++)
#pragma unroll
    for (int j = 0; j < 8; j++)
      atomicAdd(&zpre[(size_t)(b0 + tb * 4 + i) * 128 + tj * 8 + j], acc[i][j]);
}

// mu/lv bias + reparameterization; fp32 outputs, fp32 z (ws)
__global__ void zfin(const float* __restrict__ zpre, const float* __restrict__ eps,
                     const float* __restrict__ mub, const float* __restrict__ lvb,
                     float* __restrict__ out_mu, float* __restrict__ out_lv,
                     float* __restrict__ z) {
  const int i = blockIdx.x * 256 + threadIdx.x;   // B*Z = 65536
  const int b = i >> 6, j = i & 63;
  const float mu = zpre[(size_t)b * 128 + j] + mub[j];
  const float lv = zpre[(size_t)b * 128 + 64 + j] + lvb[j];
  const float zz = mu + expf(0.5f * lv) * eps[i];
  out_mu[i] = mu;
  out_lv[i] = lv;
  z[i] = zz;
}

// ---------------------------------------------------------------------------
// Fused decoder branch: fulcon sigmoid + two 2x2 sigmoid block layers + out dot.
// fw staged in LDS per mi-group. Block = 64 b x 256 m; grid (16,16). All fp32.
// ---------------------------------------------------------------------------
__global__ __launch_bounds__(256) void dec_fused(
    const float* __restrict__ z,
    const float* __restrict__ fw, const float* __restrict__ fb,
    const float* __restrict__ hw, const float* __restrict__ hb,
    const float* __restrict__ ow, const float* __restrict__ ob,
    float* __restrict__ out) {
  __shared__ __attribute__((aligned(16))) float sZ[64][68];  // [k][b]
  __shared__ float sFW[64][130];                             // [k][local fw row]
  const int tid = threadIdx.x;
  const int b0 = blockIdx.x * 64;
  const int m0 = blockIdx.y * 256;
  {
    const int r  = tid >> 2;          // b-row 0..63
    const int c0 = (tid & 3) * 16;    // k-chunk
    const float* p = z + (size_t)(b0 + r) * NZ + c0;
#pragma unroll
    for (int i = 0; i < 16; i++) sZ[c0 + i][r] = p[i];
  }

  const int bq = tid >> 6;   // 0..3 : 16-b group
  const int tm = tid & 63;   // lane -> consecutive m

  for (int mi = 0; mi < 4; mi++) {
    const int mb = m0 + mi * 64;        // m-base of this group
    __syncthreads();                    // sFW reuse + (mi==0) sZ ready
    {
      const int R0 = 2 * mb;
#pragma unroll
      for (int q = 0; q < 8; q++) {
        const int v = tid + q * 256;        // 0..2047 float4-ids
        const int grow = v >> 4;            // 0..127
        const int gk = (v & 15) * 4;
        const float4 f4 = *(const float4*)&fw[(size_t)(R0 + grow) * NZ + gk];
        sFW[gk + 0][grow] = f4.x;
        sFW[gk + 1][grow] = f4.y;
        sFW[gk + 2][grow] = f4.z;
        sFW[gk + 3][grow] = f4.w;
      }
    }
    __syncthreads();

    const int m = mb + tm;
    float acc0[16], acc1[16];
    const float bb0 = fb[2 * m], bb1 = fb[2 * m + 1];
#pragma unroll
    for (int b = 0; b < 16; b++) { acc0[b] = bb0; acc1[b] = bb1; }
#pragma unroll 8
    for (int k = 0; k < 64; k++) {
      const float2 wv2 = *(const float2*)&sFW[k][2 * tm];
      const float4 z0 = *(const float4*)&sZ[k][bq * 16 + 0];
      const float4 z1 = *(const float4*)&sZ[k][bq * 16 + 4];
      const float4 z2 = *(const float4*)&sZ[k][bq * 16 + 8];
      const float4 z3 = *(const float4*)&sZ[k][bq * 16 + 12];
      const float zv[16] = {z0.x, z0.y, z0.z, z0.w, z1.x, z1.y, z1.z, z1.w,
                            z2.x, z2.y, z2.z, z2.w, z3.x, z3.y, z3.z, z3.w};
#pragma unroll
      for (int b = 0; b < 16; b++) {
        acc0[b] += zv[b] * wv2.x;
        acc1[b] += zv[b] * wv2.y;
      }
    }
    float wv[2][4], hbv[2][2];
#pragma unroll
    for (int l = 0; l < 2; l++) {
      const float4 wp = *(const float4*)&hw[((size_t)l * NM + m) * 4];  // 2x2 [v][w]
      wv[l][0] = wp.x; wv[l][1] = wp.y; wv[l][2] = wp.z; wv[l][3] = wp.w;
      const float2 hb2 = *(const float2*)&hb[(size_t)l * NH + 2 * m];
      hbv[l][0] = hb2.x; hbv[l][1] = hb2.y;
    }
    const float2 o2 = *(const float2*)&ow[2 * m];
    const float obv = ob[m];
#pragma unroll
    for (int b = 0; b < 16; b++) {
      float a0 = sigf(acc0[b]), a1 = sigf(acc1[b]);
#pragma unroll
      for (int l = 0; l < 2; l++) {
        const float v0 = sigf(wv[l][0] * a0 + wv[l][1] * a1 + hbv[l][0]);
        const float v1 = sigf(wv[l][2] * a0 + wv[l][3] * a1 + hbv[l][1]);
        a0 = v0; a1 = v1;
      }
      out[(size_t)(b0 + bq * 16 + b) * NM + m] = a0 * o2.x + a1 * o2.y + obv;
    }
  }
}

extern "C" void kernel_launch(void* const* d_in, const int* in_sizes, int n_in,
                              void* d_out, int out_size, void* d_ws, size_t ws_size,
                              hipStream_t stream) {
  const float* x   = (const float*)d_in[0];
  const float* eps = (const float*)d_in[1];
  const float* e1w = (const float*)d_in[2];
  const float* e1b = (const float*)d_in[3];
  const float* e2w = (const float*)d_in[4];
  const float* e2b = (const float*)d_in[5];
  const float* muw = (const float*)d_in[6];
  const float* mub = (const float*)d_in[7];
  const float* lvw = (const float*)d_in[8];
  const float* lvb = (const float*)d_in[9];
  const float* mfw = (const float*)d_in[10];
  const float* mfb = (const float*)d_in[11];
  const float* mhw = (const float*)d_in[12];
  const float* mhb = (const float*)d_in[13];
  const float* mow = (const float*)d_in[14];
  const float* mob = (const float*)d_in[15];
  const float* cfw = (const float*)d_in[16];
  const float* cfb = (const float*)d_in[17];
  const float* chw = (const float*)d_in[18];
  const float* chb = (const float*)d_in[19];
  const float* cow = (const float*)d_in[20];
  const float* cob = (const float*)d_in[21];

  // d_out regions (fp32): out_x [0,4M), out_lc [4M,8M), mu, lv.
  // bf16 intermediates overlay dead byte-ranges:
  //   h1 bf16 @ bytes [0,8M)      (dead after enc2; dec-mean overwrites)
  //   xb bf16 @ bytes [16M,24M)   (dead after enc1)
  //   h2 bf16 @ bytes [16M,24M)   (overwrites xb; dead after mulv; dec-cov overwrites)
  char* ob_ = (char*)d_out;
  float* out_x  = (float*)ob_;
  float* out_lc = (float*)(ob_ + (16u << 20));
  float* out_mu = out_x + (size_t)2 * NB * NM;
  float* out_lv = out_mu + (size_t)NB * NZ;
  bf16* h1 = (bf16*)ob_;
  bf16* xb = (bf16*)(ob_ + (16u << 20));
  bf16* h2 = xb;

  // ws: zpre fp32 512KB + z fp32 256KB = 768KB (proven budget)
  float* zpre = (float*)d_ws;
  float* z    = (float*)((char*)d_ws + (1u << 19));

  cvt_f32_bf16<<<dim3(4096), 256, 0, stream>>>(x, xb, NB * NM / 4);
  zero_f32<<<dim3(512), 256, 0, stream>>>(zpre, NB * 128);
  gemm_nt<<<dim3(8, 32), 512, 0, stream>>>(xb, e1w, e1b, h1, NM, NM);
  gemm_nt<<<dim3(8, 32), 512, 0, stream>>>(h1, e2w, e2b, h2, NM, NM);
  mulv_splitk<<<dim3(16, 16), 256, 0, stream>>>(h2, muw, lvw, zpre);
  zfin<<<dim3(256), 256, 0, stream>>>(zpre, eps, mub, lvb, out_mu, out_lv, z);
  dec_fused<<<dim3(16, 16), 256, 0, stream>>>(z, mfw, mfb, mhw, mhb, mow, mob, out_x);
  dec_fused<<<dim3(16, 16), 256, 0, stream>>>(z, cfw, cfb, chw, chb, cow, cob, out_lc);
}